// Round 6
// baseline (3275.386 us; speedup 1.0000x reference)
//
#include <hip/hip_runtime.h>
#include <hip/hip_bf16.h>
#include <math.h>

// Problem constants
constexpr int NB  = 32;      // batch
constexpr int NS  = 256;     // seq len
constexpr int NE  = 1024;    // embed dim
constexpr int NH  = 1024;    // LSTM output dim (2*NHD)
constexpr int NHD = 512;     // per-direction hidden
constexpr int NG  = 2048;    // 4*NHD gates
constexpr int NP  = 16;      // prompt positions
constexpr int NBS = NB * NS; // 8192 rows
constexpr int GK  = 1024;    // GEMM K (= NE = NH)

// Persistent LSTM decomposition: UPW=16 units/WG, 32 WGs/dir, 64 total
constexpr int UPW  = 16;
constexpr int NWGD = NHD / UPW;  // 32 WGs per direction
// Gt layout: [d][slice 32][t 256][b 32][uloc 16][gate 4] fp32
constexpr size_t GT_DIR = (size_t)NWGD * 256 * 2048;   // 16.7M elems/dir

typedef __attribute__((ext_vector_type(8))) short bf16x8;
typedef __attribute__((ext_vector_type(4))) float f32x4;
typedef unsigned short u16;

__device__ __forceinline__ float sigm(float x) { return 1.0f / (1.0f + __expf(-x)); }
__device__ __forceinline__ u16 f2bf(float f) {
    union { float f; unsigned u; } v; v.f = f;
    unsigned r = v.u + 0x7FFF + ((v.u >> 16) & 1);   // RNE
    return (u16)(r >> 16);
}
__device__ __forceinline__ float bf2f(u16 b) {
    return __uint_as_float((unsigned)b << 16);
}

// ---------------------------------------------------------------------------
__global__ void k_zero(int* p) { p[threadIdx.x] = 0; }

// ---------------------------------------------------------------------------
// allb_bf[s][b][1024] (bf16) = emb[id]+ctx[id], prompt_emb at prompt slots
// ---------------------------------------------------------------------------
__global__ void k_allb(const float* __restrict__ emb, const float* __restrict__ ctx,
                       const float* __restrict__ pemb, const int* __restrict__ ids,
                       const int* __restrict__ pidx, u16* __restrict__ allb) {
    int r = blockIdx.x;            // r = b*NS + s
    int b = r >> 8, s = r & 255;
    __shared__ int ppos;
    if (threadIdx.x == 0) {
        int t = -1;
        #pragma unroll
        for (int p = 0; p < NP; ++p)
            if (pidx[b * NP + p] == s) t = p;
        ppos = t;
    }
    __syncthreads();
    int e = threadIdx.x;
    float4 v;
    if (ppos >= 0) {
        v = ((const float4*)(pemb + (size_t)ppos * NE))[e];
    } else {
        int id = ids[r];
        float4 a = ((const float4*)(emb + (size_t)id * NE))[e];
        float4 c = ((const float4*)(ctx + (size_t)id * NE))[e];
        v = make_float4(a.x + c.x, a.y + c.y, a.z + c.z, a.w + c.w);
    }
    ushort4 o;
    o.x = f2bf(v.x); o.y = f2bf(v.y); o.z = f2bf(v.z); o.w = f2bf(v.w);
    *(ushort4*)(allb + ((size_t)(s * NB + b)) * NE + e * 4) = o;
}

// ---------------------------------------------------------------------------
__global__ void k_raw(const float* __restrict__ emb, const int* __restrict__ ids,
                      float* __restrict__ out) {
    int r = blockIdx.x;
    int id = ids[r];
    ((float4*)(out + (size_t)r * NE))[threadIdx.x] =
        ((const float4*)(emb + (size_t)id * NE))[threadIdx.x];
}

// ---------------------------------------------------------------------------
// Wih ([2][2048][1024] fp32, gate-major rows) -> Wbf ([2][2048][1024] bf16,
// UNIT-MAJOR rows: n' = unit*4+gate) + combined bias in same order.
// ---------------------------------------------------------------------------
__global__ void k_wcvt(const float* __restrict__ Wih, const float* __restrict__ bih,
                       const float* __restrict__ bhh, u16* __restrict__ Wbf,
                       float* __restrict__ biasC) {
    int blk = blockIdx.x;               // [2][2048]
    int d = blk >> 11, np = blk & 2047;
    int rw = (np & 3) * 512 + (np >> 2);
    const float* src = Wih + ((size_t)d * NG + rw) * GK;
    u16* dst = Wbf + ((size_t)d * NG + np) * GK;
    int t = threadIdx.x;
    float4 v = ((const float4*)src)[t];
    ushort4 o;
    o.x = f2bf(v.x); o.y = f2bf(v.y); o.z = f2bf(v.z); o.w = f2bf(v.w);
    ((ushort4*)dst)[t] = o;
    if (t == 0)
        biasC[d * NG + np] = bih[d * NG + rw] + bhh[d * NG + rw];
}

// ---------------------------------------------------------------------------
// bf16 MFMA GEMM: Gt = A[m',k] @ Wbf[n',k]^T + biasC
// m' = t*32+b (8192), n' = unit*4+g (2048 per dir), K = 1024.
// A: bf16, k<512 from A0 + m'*astride + k, else A1 + m'*astride + (k-512).
// 128x128 tile, BK=64, 4 waves, 4x4 16x16x32 frags/wave.
// ---------------------------------------------------------------------------
__global__ __launch_bounds__(256) void k_gemm_m(const u16* __restrict__ A0,
                                                const u16* __restrict__ A1,
                                                int astride,
                                                const u16* __restrict__ W,
                                                const float* __restrict__ bc,
                                                float* __restrict__ Gt) {
    __shared__ char At[128 * 128];
    __shared__ char Wt[128 * 128];
    int tid = threadIdx.x;
    int lane = tid & 63, w = tid >> 6;
    int n0 = blockIdx.x * 128, m0 = blockIdx.y * 128;
    int r = tid >> 1, h = tid & 1;      // staging: row r, half h

    f32x4 acc[4][4];
    #pragma unroll
    for (int i = 0; i < 4; ++i)
        #pragma unroll
        for (int j = 0; j < 4; ++j) acc[i][j] = (f32x4){0.f, 0.f, 0.f, 0.f};

    unsigned rsw = (unsigned)((r & 7) << 4);
    for (int kt = 0; kt < GK; kt += 64) {
        {
            int k0 = kt + h * 32;
            const u16* asrc = (k0 < 512) ? (A0 + (size_t)(m0 + r) * astride + k0)
                                         : (A1 + (size_t)(m0 + r) * astride + (k0 - 512));
            const u16* wsrc = W + (size_t)(n0 + r) * GK + k0;
            #pragma unroll
            for (int j = 0; j < 4; ++j) {
                uint4 va = *(const uint4*)(asrc + j * 8);
                *(uint4*)(At + r * 128 + (((unsigned)(h * 64 + j * 16)) ^ rsw)) = va;
                uint4 vw = *(const uint4*)(wsrc + j * 8);
                *(uint4*)(Wt + r * 128 + (((unsigned)(h * 64 + j * 16)) ^ rsw)) = vw;
            }
        }
        __syncthreads();
        #pragma unroll
        for (int sub = 0; sub < 2; ++sub) {
            bf16x8 af[4], bfr[4];
            int kbyte = sub * 64 + (lane >> 4) * 16;
            #pragma unroll
            for (int ni = 0; ni < 4; ++ni) {
                int rr = (w & 1) * 64 + ni * 16 + (lane & 15);
                af[ni] = *(const bf16x8*)(Wt + rr * 128 + ((unsigned)kbyte ^ ((unsigned)((rr & 7) << 4))));
            }
            #pragma unroll
            for (int mi = 0; mi < 4; ++mi) {
                int rr = (w >> 1) * 64 + mi * 16 + (lane & 15);
                bfr[mi] = *(const bf16x8*)(At + rr * 128 + ((unsigned)kbyte ^ ((unsigned)((rr & 7) << 4))));
            }
            #pragma unroll
            for (int mi = 0; mi < 4; ++mi)
                #pragma unroll
                for (int ni = 0; ni < 4; ++ni)
                    acc[mi][ni] = __builtin_amdgcn_mfma_f32_16x16x32_bf16(
                        af[ni], bfr[mi], acc[mi][ni], 0, 0, 0);
        }
        __syncthreads();
    }
    // epilogue: float4 (4 gates of one unit) -> Gt[slice][t][b][uloc][g]
    #pragma unroll
    for (int mi = 0; mi < 4; ++mi) {
        int mp = m0 + (w >> 1) * 64 + mi * 16 + (lane & 15);
        int t = mp >> 5, b = mp & 31;
        #pragma unroll
        for (int ni = 0; ni < 4; ++ni) {
            int npb = n0 + (w & 1) * 64 + ni * 16 + (lane >> 4) * 4;
            int unit = npb >> 2;
            float4 bv = *(const float4*)(bc + npb);
            f32x4 a = acc[mi][ni];
            float4 o = make_float4(a[0] + bv.x, a[1] + bv.y, a[2] + bv.z, a[3] + bv.w);
            *(float4*)(Gt + ((size_t)((unit >> 4) * NS + t)) * 2048 + b * 64 + (unit & 15) * 4) = o;
        }
    }
}

// ---------------------------------------------------------------------------
// MFMA persistent LSTM recurrence, LDS-free, distributed-counter barrier.
// Grid = 64 WGs: wg&1 = dir, wg>>1 = slice (16 units). Wave w owns gate-rows
// 16w..16w+15 (units 4w..4w+3, all 4 gates) -> wfrag[16] unique per wave.
// Each wave computes BOTH batch-blocks (acc0: b 0-15, acc1: b 16-31).
// B-frags read DIRECTLY from hx_bf (plain cached 16B loads; step regions are
// first-touch per dispatch -> coherent, same argument as R4/R5 staging).
// h store: sc1 relaxed (LLC write-through). Barrier: 4 counters/dir in
// separate 64B lines, 8 relaxed adds each, poll all 4 (relaxed).
// G for step t+1 prefetched BEFORE the barrier wait.
// ---------------------------------------------------------------------------
__global__ __launch_bounds__(256) void k_lstm_d(const float* __restrict__ Gt,
                                                const float* __restrict__ Whh,
                                                u16* __restrict__ hxb,
                                                int* __restrict__ ctr) {
    int wg = blockIdx.x;
    int d = wg & 1;
    int slice = wg >> 1;            // 0..31
    int n0 = slice * UPW;
    int tid = threadIdx.x;
    int lane = tid & 63;
    int w = tid >> 6;               // wave 0..3
    int* ctrd  = ctr + d * 64;
    int* myctr = ctrd + (slice & 3) * 16;
    u16* hxd = hxb + (size_t)d * NS * NB * NHD;
    const float* Gd = Gt + (size_t)d * GT_DIR + (size_t)slice * NS * 2048;

    // resident A fragments (Whh fp32 -> bf16); per-wave-unique rows
    bf16x8 wfrag[16];
    {
        int rloc = lane & 15;
        int usub = rloc >> 2, g = rloc & 3;
        int kb = lane >> 4;
        const float* wrow = Whh + ((size_t)d * NG + g * NHD + n0 + 4 * w + usub) * NHD;
        #pragma unroll
        for (int kk = 0; kk < 16; ++kk) {
            const float* p = wrow + kk * 32 + kb * 8;
            float4 x = *(const float4*)p;
            float4 y = *(const float4*)(p + 4);
            bf16x8 wf;
            wf[0] = (short)f2bf(x.x); wf[1] = (short)f2bf(x.y);
            wf[2] = (short)f2bf(x.z); wf[3] = (short)f2bf(x.w);
            wf[4] = (short)f2bf(y.x); wf[5] = (short)f2bf(y.y);
            wf[6] = (short)f2bf(y.z); wf[7] = (short)f2bf(y.w);
            wfrag[kk] = wf;
        }
    }
    int uloc  = 4 * w + (lane >> 4);       // C-layout unit within slice
    int unitC = n0 + uloc;                 // global unit
    int bcol0 = lane & 15;                 // batch, tile 0
    int bcol1 = 16 + bcol0;                // batch, tile 1
    int kb    = lane >> 4;                 // B k-block

    float c0 = 0.f, c1 = 0.f;
    // prologue: G prefetch for step 0
    int ttp = d ? (NS - 1) : 0;
    float4 Gv0 = *(const float4*)(Gd + (size_t)ttp * 2048 + bcol0 * 64 + uloc * 4);
    float4 Gv1 = *(const float4*)(Gd + (size_t)ttp * 2048 + bcol1 * 64 + uloc * 4);

    for (int step = 0; step < NS; ++step) {
        int tt = d ? (NS - 1 - step) : step;
        f32x4 acc0 = {0.f, 0.f, 0.f, 0.f};
        f32x4 acc1 = {0.f, 0.f, 0.f, 0.f};
        if (step) {
            int tprev = d ? tt + 1 : tt - 1;
            const u16* h0 = hxd + ((size_t)tprev * NB + bcol0) * NHD + kb * 8;
            const u16* h1 = hxd + ((size_t)tprev * NB + bcol1) * NHD + kb * 8;
            #pragma unroll
            for (int kk = 0; kk < 16; ++kk) {
                bf16x8 b0 = *(const bf16x8*)(h0 + kk * 32);
                bf16x8 b1 = *(const bf16x8*)(h1 + kk * 32);
                acc0 = __builtin_amdgcn_mfma_f32_16x16x32_bf16(wfrag[kk], b0, acc0, 0, 0, 0);
                acc1 = __builtin_amdgcn_mfma_f32_16x16x32_bf16(wfrag[kk], b1, acc1, 0, 0, 0);
            }
        }
        // gates (reg q = gate q: i,f,g,o) for (unitC, bcol0/1)
        {
            float ig = sigm(acc0[0] + Gv0.x);
            float fg = sigm(acc0[1] + Gv0.y);
            float gg = tanhf(acc0[2] + Gv0.z);
            float og = sigm(acc0[3] + Gv0.w);
            c0 = fg * c0 + ig * gg;
            float hv = og * tanhf(c0);
            __hip_atomic_store(hxd + ((size_t)tt * NB + bcol0) * NHD + unitC, f2bf(hv),
                               __ATOMIC_RELAXED, __HIP_MEMORY_SCOPE_AGENT);
        }
        {
            float ig = sigm(acc1[0] + Gv1.x);
            float fg = sigm(acc1[1] + Gv1.y);
            float gg = tanhf(acc1[2] + Gv1.z);
            float og = sigm(acc1[3] + Gv1.w);
            c1 = fg * c1 + ig * gg;
            float hv = og * tanhf(c1);
            __hip_atomic_store(hxd + ((size_t)tt * NB + bcol1) * NHD + unitC, f2bf(hv),
                               __ATOMIC_RELAXED, __HIP_MEMORY_SCOPE_AGENT);
        }
        // prefetch next step's G before the wait (latency hides under barrier)
        if (step + 1 < NS) {
            int ttn = d ? tt - 1 : tt + 1;
            Gv0 = *(const float4*)(Gd + (size_t)ttn * 2048 + bcol0 * 64 + uloc * 4);
            Gv1 = *(const float4*)(Gd + (size_t)ttn * 2048 + bcol1 * 64 + uloc * 4);
        }
        asm volatile("s_waitcnt vmcnt(0)" ::: "memory");
        __syncthreads();
        if (tid == 0) {
            __hip_atomic_fetch_add(myctr, 1, __ATOMIC_RELAXED, __HIP_MEMORY_SCOPE_AGENT);
            int target = (NWGD / 4) * (step + 1);
            for (;;) {
                int a = __hip_atomic_load(ctrd +  0, __ATOMIC_RELAXED, __HIP_MEMORY_SCOPE_AGENT);
                int b = __hip_atomic_load(ctrd + 16, __ATOMIC_RELAXED, __HIP_MEMORY_SCOPE_AGENT);
                int c = __hip_atomic_load(ctrd + 32, __ATOMIC_RELAXED, __HIP_MEMORY_SCOPE_AGENT);
                int e = __hip_atomic_load(ctrd + 48, __ATOMIC_RELAXED, __HIP_MEMORY_SCOPE_AGENT);
                if (a >= target && b >= target && c >= target && e >= target) break;
                __builtin_amdgcn_s_sleep(1);
            }
        }
        __syncthreads();
    }
}

// ---------------------------------------------------------------------------
// MLP stage 1: mid[512][1024] = relu(hrow @ W1^T + b1), rows from hx_bf
// ---------------------------------------------------------------------------
__global__ __launch_bounds__(256) void k_mlp1(const u16* __restrict__ hxb,
                                              const int* __restrict__ pidx,
                                              const float* __restrict__ W1,
                                              const float* __restrict__ b1,
                                              float* __restrict__ mid) {
    __shared__ float As[16][65];
    __shared__ float Ws[16][65];
    int tid = threadIdx.x;
    int tx = tid & 15, ty = tid >> 4;
    int n0 = blockIdx.x * 64, m0 = blockIdx.y * 64;
    int lr = tid >> 2;
    int lk = (tid & 3) * 4;
    int m = m0 + lr;
    int bb = m >> 4;
    int s = pidx[m];
    float acc[4][4] = {};
    for (int kt = 0; kt < GK; kt += 16) {
        int k0 = kt + lk;
        int half = k0 >> 9;
        ushort4 av4 = *(const ushort4*)(hxb + (((size_t)(half * NS + s)) * NB + bb) * NHD + (k0 & 511));
        float4 wv = *(const float4*)(W1 + (size_t)(n0 + lr) * GK + k0);
        As[lk + 0][lr] = bf2f(av4.x); As[lk + 1][lr] = bf2f(av4.y);
        As[lk + 2][lr] = bf2f(av4.z); As[lk + 3][lr] = bf2f(av4.w);
        Ws[lk + 0][lr] = wv.x; Ws[lk + 1][lr] = wv.y;
        Ws[lk + 2][lr] = wv.z; Ws[lk + 3][lr] = wv.w;
        __syncthreads();
        #pragma unroll
        for (int kk = 0; kk < 16; ++kk) {
            float a[4], wv2[4];
            #pragma unroll
            for (int i = 0; i < 4; ++i) a[i] = As[kk][ty * 4 + i];
            #pragma unroll
            for (int j = 0; j < 4; ++j) wv2[j] = Ws[kk][tx * 4 + j];
            #pragma unroll
            for (int i = 0; i < 4; ++i)
                #pragma unroll
                for (int j = 0; j < 4; ++j) acc[i][j] += a[i] * wv2[j];
        }
        __syncthreads();
    }
    #pragma unroll
    for (int j = 0; j < 4; ++j) {
        int n = n0 + tx * 4 + j;
        float bias = b1[n];
        #pragma unroll
        for (int i = 0; i < 4; ++i)
            mid[(size_t)(m0 + ty * 4 + i) * 1024 + n] = fmaxf(acc[i][j] + bias, 0.f);
    }
}

// ---------------------------------------------------------------------------
// MLP stage 2: out[b, s] = mid @ W2^T + b2 + pemb[p], scattered to d_out.
// ---------------------------------------------------------------------------
__global__ __launch_bounds__(256) void k_mlp2(const float* __restrict__ mid,
                                              const int* __restrict__ pidx,
                                              const float* __restrict__ W2,
                                              const float* __restrict__ b2,
                                              const float* __restrict__ pemb,
                                              float* __restrict__ out) {
    __shared__ float As[16][65];
    __shared__ float Ws[16][65];
    int tid = threadIdx.x;
    int tx = tid & 15, ty = tid >> 4;
    int n0 = blockIdx.x * 64, m0 = blockIdx.y * 64;
    int lr = tid >> 2;
    int lk = (tid & 3) * 4;
    float acc[4][4] = {};
    for (int kt = 0; kt < GK; kt += 16) {
        float4 av = *(const float4*)(mid + (size_t)(m0 + lr) * GK + kt + lk);
        float4 wv = *(const float4*)(W2 + (size_t)(n0 + lr) * GK + kt + lk);
        As[lk + 0][lr] = av.x; As[lk + 1][lr] = av.y;
        As[lk + 2][lr] = av.z; As[lk + 3][lr] = av.w;
        Ws[lk + 0][lr] = wv.x; Ws[lk + 1][lr] = wv.y;
        Ws[lk + 2][lr] = wv.z; Ws[lk + 3][lr] = wv.w;
        __syncthreads();
        #pragma unroll
        for (int kk = 0; kk < 16; ++kk) {
            float a[4], wv2[4];
            #pragma unroll
            for (int i = 0; i < 4; ++i) a[i] = As[kk][ty * 4 + i];
            #pragma unroll
            for (int j = 0; j < 4; ++j) wv2[j] = Ws[kk][tx * 4 + j];
            #pragma unroll
            for (int i = 0; i < 4; ++i)
                #pragma unroll
                for (int j = 0; j < 4; ++j) acc[i][j] += a[i] * wv2[j];
        }
        __syncthreads();
    }
    #pragma unroll
    for (int i = 0; i < 4; ++i) {
        int m = m0 + ty * 4 + i;
        int bb = m >> 4, p = m & 15;
        int s = pidx[m];
        float* orow = out + ((size_t)(bb * NS + s)) * NE;
        const float* prow = pemb + (size_t)p * NE;
        #pragma unroll
        for (int j = 0; j < 4; ++j) {
            int n = n0 + tx * 4 + j;
            orow[n] = acc[i][j] + b2[n] + prow[n];
        }
    }
}

// ---------------------------------------------------------------------------
extern "C" void kernel_launch(void* const* d_in, const int* in_sizes, int n_in,
                              void* d_out, int out_size, void* d_ws, size_t ws_size,
                              hipStream_t stream) {
    const float* emb  = (const float*)d_in[0];
    const float* ctx  = (const float*)d_in[1];
    const float* pemb = (const float*)d_in[2];
    const float* Wih0 = (const float*)d_in[3];
    const float* Whh0 = (const float*)d_in[4];
    const float* bih0 = (const float*)d_in[5];
    const float* bhh0 = (const float*)d_in[6];
    const float* Wih1 = (const float*)d_in[7];
    const float* Whh1 = (const float*)d_in[8];
    const float* bih1 = (const float*)d_in[9];
    const float* bhh1 = (const float*)d_in[10];
    const float* W1   = (const float*)d_in[11];
    const float* b1   = (const float*)d_in[12];
    const float* W2   = (const float*)d_in[13];
    const float* b2   = (const float*)d_in[14];
    const int* ids    = (const int*)d_in[15];
    const int* pidx   = (const int*)d_in[16];
    float* out = (float*)d_out;

    // Workspace layout (bytes):
    //   Gt:    [2][32][256][2048] f32 = 134217728
    //   allb:  [256][32][1024] bf16   =  16777216
    //   hx_bf: [2][256][32][512] bf16 =  16777216
    //   Wbf:   [2][2048][1024] bf16   =   8388608
    //   biasC: [2][2048] f32          =     16384
    //   mid:   [512][1024] f32        =   2097152
    //   ctr:   256 ints (2 layers x 2 dirs x 4 counters x 16-int lines)
    char* ws = (char*)d_ws;
    float* Gt    = (float*)ws;
    u16*   allb  = (u16*)(ws + 134217728u);
    u16*   hx    = (u16*)(ws + 150994944u);
    u16*   Wbf   = (u16*)(ws + 167772160u);
    float* biasC = (float*)(ws + 176160768u);
    float* mid   = (float*)(ws + 176177152u);
    int*   ctr   = (int*)(ws + 178274304u);

    k_zero<<<dim3(1), dim3(256), 0, stream>>>(ctr);
    k_allb<<<dim3(NBS), dim3(256), 0, stream>>>(emb, ctx, pemb, ids, pidx, allb);

    // Layer 0
    k_wcvt<<<dim3(2 * NG), dim3(256), 0, stream>>>(Wih0, bih0, bhh0, Wbf, biasC);
    for (int d = 0; d < 2; ++d)
        k_gemm_m<<<dim3(NG / 128, NBS / 128), dim3(256), 0, stream>>>(
            allb, allb + 512, 1024, Wbf + (size_t)d * NG * GK, biasC + d * NG,
            Gt + (size_t)d * GT_DIR);
    k_lstm_d<<<dim3(2 * NWGD), dim3(256), 0, stream>>>(Gt, Whh0, hx, ctr);

    k_raw<<<dim3(NBS), dim3(256), 0, stream>>>(emb, ids, out);

    // Layer 1 (A = hx_bf, dir halves)
    k_wcvt<<<dim3(2 * NG), dim3(256), 0, stream>>>(Wih1, bih1, bhh1, Wbf, biasC);
    for (int d = 0; d < 2; ++d)
        k_gemm_m<<<dim3(NG / 128, NBS / 128), dim3(256), 0, stream>>>(
            hx, hx + (size_t)NS * NB * NHD, 512, Wbf + (size_t)d * NG * GK,
            biasC + d * NG, Gt + (size_t)d * GT_DIR);
    k_lstm_d<<<dim3(2 * NWGD), dim3(256), 0, stream>>>(Gt, Whh1, hx, ctr + 128);

    // MLP head at prompt rows
    k_mlp1<<<dim3(16, 8), dim3(256), 0, stream>>>(hx, pidx, W1, b1, mid);
    k_mlp2<<<dim3(16, 8), dim3(256), 0, stream>>>(mid, pidx, W2, b2, pemb, out);
}

// Round 7
// 2417.786 us; speedup vs baseline: 1.3547x; 1.3547x over previous
//
#include <hip/hip_runtime.h>
#include <hip/hip_bf16.h>
#include <math.h>

// Problem constants
constexpr int NB  = 32;      // batch
constexpr int NS  = 256;     // seq len
constexpr int NE  = 1024;    // embed dim
constexpr int NH  = 1024;    // LSTM output dim (2*NHD)
constexpr int NHD = 512;     // per-direction hidden
constexpr int NG  = 2048;    // 4*NHD gates
constexpr int NP  = 16;      // prompt positions
constexpr int NBS = NB * NS; // 8192 rows
constexpr int GK  = 1024;    // GEMM K (= NE = NH)

// Persistent LSTM decomposition: UPW=16 units/WG, 32 WGs/dir, 64 total
constexpr int UPW  = 16;
constexpr int NWGD = NHD / UPW;  // 32 WGs per direction
// Gt layout: [d][slice 32][t 256][b 32][uloc 16][gate 4] fp32
constexpr size_t GT_DIR = (size_t)NWGD * 256 * 2048;   // 16.7M elems/dir

typedef __attribute__((ext_vector_type(8))) short bf16x8;
typedef __attribute__((ext_vector_type(4))) float f32x4;
typedef unsigned short u16;

__device__ __forceinline__ float sigm(float x) { return 1.0f / (1.0f + __expf(-x)); }
__device__ __forceinline__ u16 f2bf(float f) {
    union { float f; unsigned u; } v; v.f = f;
    unsigned r = v.u + 0x7FFF + ((v.u >> 16) & 1);   // RNE
    return (u16)(r >> 16);
}
__device__ __forceinline__ float bf2f(u16 b) {
    return __uint_as_float((unsigned)b << 16);
}

// ---------------------------------------------------------------------------
__global__ void k_zero(int* p) { p[threadIdx.x] = 0; }

// ---------------------------------------------------------------------------
// allb_bf[s][b][1024] (bf16) = emb[id]+ctx[id], prompt_emb at prompt slots
// ---------------------------------------------------------------------------
__global__ void k_allb(const float* __restrict__ emb, const float* __restrict__ ctx,
                       const float* __restrict__ pemb, const int* __restrict__ ids,
                       const int* __restrict__ pidx, u16* __restrict__ allb) {
    int r = blockIdx.x;            // r = b*NS + s
    int b = r >> 8, s = r & 255;
    __shared__ int ppos;
    if (threadIdx.x == 0) {
        int t = -1;
        #pragma unroll
        for (int p = 0; p < NP; ++p)
            if (pidx[b * NP + p] == s) t = p;
        ppos = t;
    }
    __syncthreads();
    int e = threadIdx.x;
    float4 v;
    if (ppos >= 0) {
        v = ((const float4*)(pemb + (size_t)ppos * NE))[e];
    } else {
        int id = ids[r];
        float4 a = ((const float4*)(emb + (size_t)id * NE))[e];
        float4 c = ((const float4*)(ctx + (size_t)id * NE))[e];
        v = make_float4(a.x + c.x, a.y + c.y, a.z + c.z, a.w + c.w);
    }
    ushort4 o;
    o.x = f2bf(v.x); o.y = f2bf(v.y); o.z = f2bf(v.z); o.w = f2bf(v.w);
    *(ushort4*)(allb + ((size_t)(s * NB + b)) * NE + e * 4) = o;
}

// ---------------------------------------------------------------------------
__global__ void k_raw(const float* __restrict__ emb, const int* __restrict__ ids,
                      float* __restrict__ out) {
    int r = blockIdx.x;
    int id = ids[r];
    ((float4*)(out + (size_t)r * NE))[threadIdx.x] =
        ((const float4*)(emb + (size_t)id * NE))[threadIdx.x];
}

// ---------------------------------------------------------------------------
// Wih ([2][2048][1024] fp32, gate-major rows) -> Wbf ([2][2048][1024] bf16,
// UNIT-MAJOR rows: n' = unit*4+gate) + combined bias in same order.
// ---------------------------------------------------------------------------
__global__ void k_wcvt(const float* __restrict__ Wih, const float* __restrict__ bih,
                       const float* __restrict__ bhh, u16* __restrict__ Wbf,
                       float* __restrict__ biasC) {
    int blk = blockIdx.x;               // [2][2048]
    int d = blk >> 11, np = blk & 2047;
    int rw = (np & 3) * 512 + (np >> 2);
    const float* src = Wih + ((size_t)d * NG + rw) * GK;
    u16* dst = Wbf + ((size_t)d * NG + np) * GK;
    int t = threadIdx.x;
    float4 v = ((const float4*)src)[t];
    ushort4 o;
    o.x = f2bf(v.x); o.y = f2bf(v.y); o.z = f2bf(v.z); o.w = f2bf(v.w);
    ((ushort4*)dst)[t] = o;
    if (t == 0)
        biasC[d * NG + np] = bih[d * NG + rw] + bhh[d * NG + rw];
}

// ---------------------------------------------------------------------------
// bf16 MFMA GEMM: Gt = A[m',k] @ Wbf[n',k]^T + biasC
// m' = t*32+b (8192), n' = unit*4+g (2048 per dir), K = 1024.
// A: bf16, k<512 from A0 + m'*astride + k, else A1 + m'*astride + (k-512).
// 128x128 tile, BK=64, 4 waves, 4x4 16x16x32 frags/wave.
// ---------------------------------------------------------------------------
__global__ __launch_bounds__(256) void k_gemm_m(const u16* __restrict__ A0,
                                                const u16* __restrict__ A1,
                                                int astride,
                                                const u16* __restrict__ W,
                                                const float* __restrict__ bc,
                                                float* __restrict__ Gt) {
    __shared__ char At[128 * 128];
    __shared__ char Wt[128 * 128];
    int tid = threadIdx.x;
    int lane = tid & 63, w = tid >> 6;
    int n0 = blockIdx.x * 128, m0 = blockIdx.y * 128;
    int r = tid >> 1, h = tid & 1;      // staging: row r, half h

    f32x4 acc[4][4];
    #pragma unroll
    for (int i = 0; i < 4; ++i)
        #pragma unroll
        for (int j = 0; j < 4; ++j) acc[i][j] = (f32x4){0.f, 0.f, 0.f, 0.f};

    unsigned rsw = (unsigned)((r & 7) << 4);
    for (int kt = 0; kt < GK; kt += 64) {
        {
            int k0 = kt + h * 32;
            const u16* asrc = (k0 < 512) ? (A0 + (size_t)(m0 + r) * astride + k0)
                                         : (A1 + (size_t)(m0 + r) * astride + (k0 - 512));
            const u16* wsrc = W + (size_t)(n0 + r) * GK + k0;
            #pragma unroll
            for (int j = 0; j < 4; ++j) {
                uint4 va = *(const uint4*)(asrc + j * 8);
                *(uint4*)(At + r * 128 + (((unsigned)(h * 64 + j * 16)) ^ rsw)) = va;
                uint4 vw = *(const uint4*)(wsrc + j * 8);
                *(uint4*)(Wt + r * 128 + (((unsigned)(h * 64 + j * 16)) ^ rsw)) = vw;
            }
        }
        __syncthreads();
        #pragma unroll
        for (int sub = 0; sub < 2; ++sub) {
            bf16x8 af[4], bfr[4];
            int kbyte = sub * 64 + (lane >> 4) * 16;
            #pragma unroll
            for (int ni = 0; ni < 4; ++ni) {
                int rr = (w & 1) * 64 + ni * 16 + (lane & 15);
                af[ni] = *(const bf16x8*)(Wt + rr * 128 + ((unsigned)kbyte ^ ((unsigned)((rr & 7) << 4))));
            }
            #pragma unroll
            for (int mi = 0; mi < 4; ++mi) {
                int rr = (w >> 1) * 64 + mi * 16 + (lane & 15);
                bfr[mi] = *(const bf16x8*)(At + rr * 128 + ((unsigned)kbyte ^ ((unsigned)((rr & 7) << 4))));
            }
            #pragma unroll
            for (int mi = 0; mi < 4; ++mi)
                #pragma unroll
                for (int ni = 0; ni < 4; ++ni)
                    acc[mi][ni] = __builtin_amdgcn_mfma_f32_16x16x32_bf16(
                        af[ni], bfr[mi], acc[mi][ni], 0, 0, 0);
        }
        __syncthreads();
    }
    // epilogue: float4 (4 gates of one unit) -> Gt[slice][t][b][uloc][g]
    #pragma unroll
    for (int mi = 0; mi < 4; ++mi) {
        int mp = m0 + (w >> 1) * 64 + mi * 16 + (lane & 15);
        int t = mp >> 5, b = mp & 31;
        #pragma unroll
        for (int ni = 0; ni < 4; ++ni) {
            int npb = n0 + (w & 1) * 64 + ni * 16 + (lane >> 4) * 4;
            int unit = npb >> 2;
            float4 bv = *(const float4*)(bc + npb);
            f32x4 a = acc[mi][ni];
            float4 o = make_float4(a[0] + bv.x, a[1] + bv.y, a[2] + bv.z, a[3] + bv.w);
            *(float4*)(Gt + ((size_t)((unit >> 4) * NS + t)) * 2048 + b * 64 + (unit & 15) * 4) = o;
        }
    }
}

// ---------------------------------------------------------------------------
// MFMA persistent LSTM recurrence: UPW=16, LDS-staged B, distributed barrier.
// Grid = 64 WGs: wg&1 = dir, wg>>1 = slice (16 units). Wave w owns gate-rows
// 16w..16w+15 (units 4w..4w+3 x 4 gates), wfrag[16] unique per wave; each
// wave computes BOTH batch halves (acc0: b0-15, acc1: b16-31) from a 32KB
// XOR-swizzled bf16 LDS copy of h (single coalesced burst per step -> one
// LLC latency round, not VGPR-limited like R6's direct loads).
// Step tail: h stores (sc1 relaxed) -> vmcnt(0) -> sync -> counter add ->
// G prefetch for t+1 (hides under poll) -> poll 4 counters -> sync.
// ---------------------------------------------------------------------------
__global__ __launch_bounds__(256) void k_lstm_s(const float* __restrict__ Gt,
                                                const float* __restrict__ Whh,
                                                u16* __restrict__ hxb,
                                                int* __restrict__ ctr) {
    __shared__ char hlds[NB * NHD * 2];    // 32 KB bf16, swizzled
    int wg = blockIdx.x;
    int d = wg & 1;
    int slice = wg >> 1;            // 0..31
    int n0 = slice * UPW;
    int tid = threadIdx.x;
    int lane = tid & 63;
    int w = tid >> 6;               // wave 0..3
    int* ctrd  = ctr + d * 64;
    int* myctr = ctrd + (slice & 3) * 16;
    u16* hxd = hxb + (size_t)d * NS * NB * NHD;
    const float* Gd = Gt + (size_t)d * GT_DIR + (size_t)slice * NS * 2048;

    // resident A fragments (Whh fp32 -> bf16); per-wave-unique rows
    bf16x8 wfrag[16];
    {
        int rloc = lane & 15;
        int usub = rloc >> 2, g = rloc & 3;
        int kb = lane >> 4;
        const float* wrow = Whh + ((size_t)d * NG + g * NHD + n0 + 4 * w + usub) * NHD;
        #pragma unroll
        for (int kk = 0; kk < 16; ++kk) {
            const float* p = wrow + kk * 32 + kb * 8;
            float4 x = *(const float4*)p;
            float4 y = *(const float4*)(p + 4);
            bf16x8 wf;
            wf[0] = (short)f2bf(x.x); wf[1] = (short)f2bf(x.y);
            wf[2] = (short)f2bf(x.z); wf[3] = (short)f2bf(x.w);
            wf[4] = (short)f2bf(y.x); wf[5] = (short)f2bf(y.y);
            wf[6] = (short)f2bf(y.z); wf[7] = (short)f2bf(y.w);
            wfrag[kk] = wf;
        }
    }
    int uloc  = 4 * w + (lane >> 4);       // C-layout unit within slice
    int unitC = n0 + uloc;                 // global unit
    int bcol0 = lane & 15;                 // batch, tile 0
    int bcol1 = 16 + bcol0;                // batch, tile 1
    int kb    = lane >> 4;                 // B k-block
    int c8 = tid & 7, bRow = tid >> 3;     // staging role

    float c0 = 0.f, c1 = 0.f;
    // prologue: G prefetch for step 0
    int ttp = d ? (NS - 1) : 0;
    float4 Gv0 = *(const float4*)(Gd + (size_t)ttp * 2048 + bcol0 * 64 + uloc * 4);
    float4 Gv1 = *(const float4*)(Gd + (size_t)ttp * 2048 + bcol1 * 64 + uloc * 4);

    for (int step = 0; step < NS; ++step) {
        int tt = d ? (NS - 1 - step) : step;
        f32x4 acc0 = {0.f, 0.f, 0.f, 0.f};
        f32x4 acc1 = {0.f, 0.f, 0.f, 0.f};
        if (step) {
            int tprev = d ? tt + 1 : tt - 1;
            // stage hx_bf[tprev] (32KB) -> swizzled LDS: one coalesced burst
            const u16* srow = hxd + ((size_t)tprev * NB + bRow) * NHD;
            char* dstrow = hlds + bRow * 1024;
            unsigned rsw = (unsigned)((bRow & 7) << 4);
            #pragma unroll
            for (int i = 0; i < 8; ++i) {
                uint4 v = *(const uint4*)(srow + c8 * 64 + i * 8);
                *(uint4*)(dstrow + (((unsigned)(c8 * 128 + i * 16)) ^ rsw)) = v;
            }
            __syncthreads();
            const char* b0base = hlds + bcol0 * 1024;
            const char* b1base = hlds + bcol1 * 1024;
            unsigned s0 = (unsigned)((bcol0 & 7) << 4);
            unsigned s1 = (unsigned)((bcol1 & 7) << 4);
            #pragma unroll
            for (int kk = 0; kk < 16; ++kk) {
                bf16x8 b0 = *(const bf16x8*)(b0base + (((unsigned)(kk * 64 + kb * 16)) ^ s0));
                bf16x8 b1 = *(const bf16x8*)(b1base + (((unsigned)(kk * 64 + kb * 16)) ^ s1));
                acc0 = __builtin_amdgcn_mfma_f32_16x16x32_bf16(wfrag[kk], b0, acc0, 0, 0, 0);
                acc1 = __builtin_amdgcn_mfma_f32_16x16x32_bf16(wfrag[kk], b1, acc1, 0, 0, 0);
            }
            // (LDS-read-done ordering provided by the pre-add __syncthreads)
        }
        // gates (reg q = gate q: i,f,g,o) for (unitC, bcol0/1)
        {
            float ig = sigm(acc0[0] + Gv0.x);
            float fg = sigm(acc0[1] + Gv0.y);
            float gg = tanhf(acc0[2] + Gv0.z);
            float og = sigm(acc0[3] + Gv0.w);
            c0 = fg * c0 + ig * gg;
            float hv = og * tanhf(c0);
            __hip_atomic_store(hxd + ((size_t)tt * NB + bcol0) * NHD + unitC, f2bf(hv),
                               __ATOMIC_RELAXED, __HIP_MEMORY_SCOPE_AGENT);
        }
        {
            float ig = sigm(acc1[0] + Gv1.x);
            float fg = sigm(acc1[1] + Gv1.y);
            float gg = tanhf(acc1[2] + Gv1.z);
            float og = sigm(acc1[3] + Gv1.w);
            c1 = fg * c1 + ig * gg;
            float hv = og * tanhf(c1);
            __hip_atomic_store(hxd + ((size_t)tt * NB + bcol1) * NHD + unitC, f2bf(hv),
                               __ATOMIC_RELAXED, __HIP_MEMORY_SCOPE_AGENT);
        }
        asm volatile("s_waitcnt vmcnt(0)" ::: "memory");
        __syncthreads();           // also orders LDS reads vs next staging
        if (tid == 0)
            __hip_atomic_fetch_add(myctr, 1, __ATOMIC_RELAXED, __HIP_MEMORY_SCOPE_AGENT);
        // prefetch next step's G while tid0 polls (latency fully hidden)
        if (step + 1 < NS) {
            int ttn = d ? tt - 1 : tt + 1;
            Gv0 = *(const float4*)(Gd + (size_t)ttn * 2048 + bcol0 * 64 + uloc * 4);
            Gv1 = *(const float4*)(Gd + (size_t)ttn * 2048 + bcol1 * 64 + uloc * 4);
        }
        asm volatile("" ::: "memory");   // pin prefetch issue before poll
        if (tid == 0) {
            int target = (NWGD / 4) * (step + 1);
            for (;;) {
                int a = __hip_atomic_load(ctrd +  0, __ATOMIC_RELAXED, __HIP_MEMORY_SCOPE_AGENT);
                int b = __hip_atomic_load(ctrd + 16, __ATOMIC_RELAXED, __HIP_MEMORY_SCOPE_AGENT);
                int c = __hip_atomic_load(ctrd + 32, __ATOMIC_RELAXED, __HIP_MEMORY_SCOPE_AGENT);
                int e = __hip_atomic_load(ctrd + 48, __ATOMIC_RELAXED, __HIP_MEMORY_SCOPE_AGENT);
                if (a >= target && b >= target && c >= target && e >= target) break;
                __builtin_amdgcn_s_sleep(1);
            }
        }
        __syncthreads();
    }
}

// ---------------------------------------------------------------------------
// MLP stage 1: mid[512][1024] = relu(hrow @ W1^T + b1), rows from hx_bf
// ---------------------------------------------------------------------------
__global__ __launch_bounds__(256) void k_mlp1(const u16* __restrict__ hxb,
                                              const int* __restrict__ pidx,
                                              const float* __restrict__ W1,
                                              const float* __restrict__ b1,
                                              float* __restrict__ mid) {
    __shared__ float As[16][65];
    __shared__ float Ws[16][65];
    int tid = threadIdx.x;
    int tx = tid & 15, ty = tid >> 4;
    int n0 = blockIdx.x * 64, m0 = blockIdx.y * 64;
    int lr = tid >> 2;
    int lk = (tid & 3) * 4;
    int m = m0 + lr;
    int bb = m >> 4;
    int s = pidx[m];
    float acc[4][4] = {};
    for (int kt = 0; kt < GK; kt += 16) {
        int k0 = kt + lk;
        int half = k0 >> 9;
        ushort4 av4 = *(const ushort4*)(hxb + (((size_t)(half * NS + s)) * NB + bb) * NHD + (k0 & 511));
        float4 wv = *(const float4*)(W1 + (size_t)(n0 + lr) * GK + k0);
        As[lk + 0][lr] = bf2f(av4.x); As[lk + 1][lr] = bf2f(av4.y);
        As[lk + 2][lr] = bf2f(av4.z); As[lk + 3][lr] = bf2f(av4.w);
        Ws[lk + 0][lr] = wv.x; Ws[lk + 1][lr] = wv.y;
        Ws[lk + 2][lr] = wv.z; Ws[lk + 3][lr] = wv.w;
        __syncthreads();
        #pragma unroll
        for (int kk = 0; kk < 16; ++kk) {
            float a[4], wv2[4];
            #pragma unroll
            for (int i = 0; i < 4; ++i) a[i] = As[kk][ty * 4 + i];
            #pragma unroll
            for (int j = 0; j < 4; ++j) wv2[j] = Ws[kk][tx * 4 + j];
            #pragma unroll
            for (int i = 0; i < 4; ++i)
                #pragma unroll
                for (int j = 0; j < 4; ++j) acc[i][j] += a[i] * wv2[j];
        }
        __syncthreads();
    }
    #pragma unroll
    for (int j = 0; j < 4; ++j) {
        int n = n0 + tx * 4 + j;
        float bias = b1[n];
        #pragma unroll
        for (int i = 0; i < 4; ++i)
            mid[(size_t)(m0 + ty * 4 + i) * 1024 + n] = fmaxf(acc[i][j] + bias, 0.f);
    }
}

// ---------------------------------------------------------------------------
// MLP stage 2: out[b, s] = mid @ W2^T + b2 + pemb[p], scattered to d_out.
// ---------------------------------------------------------------------------
__global__ __launch_bounds__(256) void k_mlp2(const float* __restrict__ mid,
                                              const int* __restrict__ pidx,
                                              const float* __restrict__ W2,
                                              const float* __restrict__ b2,
                                              const float* __restrict__ pemb,
                                              float* __restrict__ out) {
    __shared__ float As[16][65];
    __shared__ float Ws[16][65];
    int tid = threadIdx.x;
    int tx = tid & 15, ty = tid >> 4;
    int n0 = blockIdx.x * 64, m0 = blockIdx.y * 64;
    int lr = tid >> 2;
    int lk = (tid & 3) * 4;
    float acc[4][4] = {};
    for (int kt = 0; kt < GK; kt += 16) {
        float4 av = *(const float4*)(mid + (size_t)(m0 + lr) * GK + kt + lk);
        float4 wv = *(const float4*)(W2 + (size_t)(n0 + lr) * GK + kt + lk);
        As[lk + 0][lr] = av.x; As[lk + 1][lr] = av.y;
        As[lk + 2][lr] = av.z; As[lk + 3][lr] = av.w;
        Ws[lk + 0][lr] = wv.x; Ws[lk + 1][lr] = wv.y;
        Ws[lk + 2][lr] = wv.z; Ws[lk + 3][lr] = wv.w;
        __syncthreads();
        #pragma unroll
        for (int kk = 0; kk < 16; ++kk) {
            float a[4], wv2[4];
            #pragma unroll
            for (int i = 0; i < 4; ++i) a[i] = As[kk][ty * 4 + i];
            #pragma unroll
            for (int j = 0; j < 4; ++j) wv2[j] = Ws[kk][tx * 4 + j];
            #pragma unroll
            for (int i = 0; i < 4; ++i)
                #pragma unroll
                for (int j = 0; j < 4; ++j) acc[i][j] += a[i] * wv2[j];
        }
        __syncthreads();
    }
    #pragma unroll
    for (int i = 0; i < 4; ++i) {
        int m = m0 + ty * 4 + i;
        int bb = m >> 4, p = m & 15;
        int s = pidx[m];
        float* orow = out + ((size_t)(bb * NS + s)) * NE;
        const float* prow = pemb + (size_t)p * NE;
        #pragma unroll
        for (int j = 0; j < 4; ++j) {
            int n = n0 + tx * 4 + j;
            orow[n] = acc[i][j] + b2[n] + prow[n];
        }
    }
}

// ---------------------------------------------------------------------------
extern "C" void kernel_launch(void* const* d_in, const int* in_sizes, int n_in,
                              void* d_out, int out_size, void* d_ws, size_t ws_size,
                              hipStream_t stream) {
    const float* emb  = (const float*)d_in[0];
    const float* ctx  = (const float*)d_in[1];
    const float* pemb = (const float*)d_in[2];
    const float* Wih0 = (const float*)d_in[3];
    const float* Whh0 = (const float*)d_in[4];
    const float* bih0 = (const float*)d_in[5];
    const float* bhh0 = (const float*)d_in[6];
    const float* Wih1 = (const float*)d_in[7];
    const float* Whh1 = (const float*)d_in[8];
    const float* bih1 = (const float*)d_in[9];
    const float* bhh1 = (const float*)d_in[10];
    const float* W1   = (const float*)d_in[11];
    const float* b1   = (const float*)d_in[12];
    const float* W2   = (const float*)d_in[13];
    const float* b2   = (const float*)d_in[14];
    const int* ids    = (const int*)d_in[15];
    const int* pidx   = (const int*)d_in[16];
    float* out = (float*)d_out;

    // Workspace layout (bytes):
    //   Gt:    [2][32][256][2048] f32 = 134217728
    //   allb:  [256][32][1024] bf16   =  16777216
    //   hx_bf: [2][256][32][512] bf16 =  16777216
    //   Wbf:   [2][2048][1024] bf16   =   8388608
    //   biasC: [2][2048] f32          =     16384
    //   mid:   [512][1024] f32        =   2097152
    //   ctr:   256 ints (2 layers x 2 dirs x 4 counters x 16-int lines)
    char* ws = (char*)d_ws;
    float* Gt    = (float*)ws;
    u16*   allb  = (u16*)(ws + 134217728u);
    u16*   hx    = (u16*)(ws + 150994944u);
    u16*   Wbf   = (u16*)(ws + 167772160u);
    float* biasC = (float*)(ws + 176160768u);
    float* mid   = (float*)(ws + 176177152u);
    int*   ctr   = (int*)(ws + 178274304u);

    k_zero<<<dim3(1), dim3(256), 0, stream>>>(ctr);
    k_allb<<<dim3(NBS), dim3(256), 0, stream>>>(emb, ctx, pemb, ids, pidx, allb);

    // Layer 0
    k_wcvt<<<dim3(2 * NG), dim3(256), 0, stream>>>(Wih0, bih0, bhh0, Wbf, biasC);
    for (int d = 0; d < 2; ++d)
        k_gemm_m<<<dim3(NG / 128, NBS / 128), dim3(256), 0, stream>>>(
            allb, allb + 512, 1024, Wbf + (size_t)d * NG * GK, biasC + d * NG,
            Gt + (size_t)d * GT_DIR);
    k_lstm_s<<<dim3(2 * NWGD), dim3(256), 0, stream>>>(Gt, Whh0, hx, ctr);

    k_raw<<<dim3(NBS), dim3(256), 0, stream>>>(emb, ids, out);

    // Layer 1 (A = hx_bf, dir halves)
    k_wcvt<<<dim3(2 * NG), dim3(256), 0, stream>>>(Wih1, bih1, bhh1, Wbf, biasC);
    for (int d = 0; d < 2; ++d)
        k_gemm_m<<<dim3(NG / 128, NBS / 128), dim3(256), 0, stream>>>(
            hx, hx + (size_t)NS * NB * NHD, 512, Wbf + (size_t)d * NG * GK,
            biasC + d * NG, Gt + (size_t)d * GT_DIR);
    k_lstm_s<<<dim3(2 * NWGD), dim3(256), 0, stream>>>(Gt, Whh1, hx, ctr + 128);

    // MLP head at prompt rows
    k_mlp1<<<dim3(16, 8), dim3(256), 0, stream>>>(hx, pidx, W1, b1, mid);
    k_mlp2<<<dim3(16, 8), dim3(256), 0, stream>>>(mid, pidx, W2, b2, pemb, out);
}

// Round 9
// 2363.278 us; speedup vs baseline: 1.3860x; 1.0231x over previous
//
#include <hip/hip_runtime.h>
#include <hip/hip_bf16.h>
#include <math.h>

// Problem constants
constexpr int NB  = 32;      // batch
constexpr int NS  = 256;     // seq len
constexpr int NE  = 1024;    // embed dim
constexpr int NH  = 1024;    // LSTM output dim (2*NHD)
constexpr int NHD = 512;     // per-direction hidden
constexpr int NG  = 2048;    // 4*NHD gates
constexpr int NP  = 16;      // prompt positions
constexpr int NBS = NB * NS; // 8192 rows
constexpr int GK  = 1024;    // GEMM K (= NE = NH)

// Persistent LSTM decomposition: UPW=16 units/WG, 32 WGs/dir, 64 total
constexpr int UPW  = 16;
constexpr int NWGD = NHD / UPW;  // 32 WGs per direction
// Gt layout: [d][slice 32][t 256][b 32][uloc 16][gate 4] fp32
constexpr size_t GT_DIR = (size_t)NWGD * 256 * 2048;   // 16.7M elems/dir

typedef __attribute__((ext_vector_type(8))) short bf16x8;
typedef __attribute__((ext_vector_type(4))) float f32x4;
typedef unsigned short u16;

__device__ __forceinline__ float sigm(float x) { return 1.0f / (1.0f + __expf(-x)); }
__device__ __forceinline__ u16 f2bf(float f) {
    union { float f; unsigned u; } v; v.f = f;
    unsigned r = v.u + 0x7FFF + ((v.u >> 16) & 1);   // RNE
    return (u16)(r >> 16);
}
__device__ __forceinline__ float bf2f(u16 b) {
    return __uint_as_float((unsigned)b << 16);
}

// ---------------------------------------------------------------------------
__global__ void k_zero(int* p) { p[blockIdx.x * 256 + threadIdx.x] = 0; }

// ---------------------------------------------------------------------------
// allb_bf[s][b][1024] (bf16) = emb[id]+ctx[id], prompt_emb at prompt slots
// ---------------------------------------------------------------------------
__global__ void k_allb(const float* __restrict__ emb, const float* __restrict__ ctx,
                       const float* __restrict__ pemb, const int* __restrict__ ids,
                       const int* __restrict__ pidx, u16* __restrict__ allb) {
    int r = blockIdx.x;            // r = b*NS + s
    int b = r >> 8, s = r & 255;
    __shared__ int ppos;
    if (threadIdx.x == 0) {
        int t = -1;
        #pragma unroll
        for (int p = 0; p < NP; ++p)
            if (pidx[b * NP + p] == s) t = p;
        ppos = t;
    }
    __syncthreads();
    int e = threadIdx.x;
    float4 v;
    if (ppos >= 0) {
        v = ((const float4*)(pemb + (size_t)ppos * NE))[e];
    } else {
        int id = ids[r];
        float4 a = ((const float4*)(emb + (size_t)id * NE))[e];
        float4 c = ((const float4*)(ctx + (size_t)id * NE))[e];
        v = make_float4(a.x + c.x, a.y + c.y, a.z + c.z, a.w + c.w);
    }
    ushort4 o;
    o.x = f2bf(v.x); o.y = f2bf(v.y); o.z = f2bf(v.z); o.w = f2bf(v.w);
    *(ushort4*)(allb + ((size_t)(s * NB + b)) * NE + e * 4) = o;
}

// ---------------------------------------------------------------------------
__global__ void k_raw(const float* __restrict__ emb, const int* __restrict__ ids,
                      float* __restrict__ out) {
    int r = blockIdx.x;
    int id = ids[r];
    ((float4*)(out + (size_t)r * NE))[threadIdx.x] =
        ((const float4*)(emb + (size_t)id * NE))[threadIdx.x];
}

// ---------------------------------------------------------------------------
// Wih ([2][2048][1024] fp32, gate-major rows) -> Wbf (bf16, UNIT-MAJOR rows:
// n' = unit*4+gate) + combined bias in same order.
// ---------------------------------------------------------------------------
__global__ void k_wcvt(const float* __restrict__ Wih, const float* __restrict__ bih,
                       const float* __restrict__ bhh, u16* __restrict__ Wbf,
                       float* __restrict__ biasC) {
    int blk = blockIdx.x;               // [2][2048]
    int d = blk >> 11, np = blk & 2047;
    int rw = (np & 3) * 512 + (np >> 2);
    const float* src = Wih + ((size_t)d * NG + rw) * GK;
    u16* dst = Wbf + ((size_t)d * NG + np) * GK;
    int t = threadIdx.x;
    float4 v = ((const float4*)src)[t];
    ushort4 o;
    o.x = f2bf(v.x); o.y = f2bf(v.y); o.z = f2bf(v.z); o.w = f2bf(v.w);
    ((ushort4*)dst)[t] = o;
    if (t == 0)
        biasC[d * NG + np] = bih[d * NG + rw] + bhh[d * NG + rw];
}

// ---------------------------------------------------------------------------
// bf16 MFMA GEMM: Gt = A[m',k] @ Wbf[n',k]^T + biasC  (proven R5 structure)
// ---------------------------------------------------------------------------
__global__ __launch_bounds__(256) void k_gemm_m(const u16* __restrict__ A0,
                                                const u16* __restrict__ A1,
                                                int astride,
                                                const u16* __restrict__ W,
                                                const float* __restrict__ bc,
                                                float* __restrict__ Gt) {
    __shared__ char At[128 * 128];
    __shared__ char Wt[128 * 128];
    int tid = threadIdx.x;
    int lane = tid & 63, w = tid >> 6;
    int n0 = blockIdx.x * 128, m0 = blockIdx.y * 128;
    int r = tid >> 1, h = tid & 1;      // staging: row r, half h

    f32x4 acc[4][4];
    #pragma unroll
    for (int i = 0; i < 4; ++i)
        #pragma unroll
        for (int j = 0; j < 4; ++j) acc[i][j] = (f32x4){0.f, 0.f, 0.f, 0.f};

    unsigned rsw = (unsigned)((r & 7) << 4);
    for (int kt = 0; kt < GK; kt += 64) {
        {
            int k0 = kt + h * 32;
            const u16* asrc = (k0 < 512) ? (A0 + (size_t)(m0 + r) * astride + k0)
                                         : (A1 + (size_t)(m0 + r) * astride + (k0 - 512));
            const u16* wsrc = W + (size_t)(n0 + r) * GK + k0;
            #pragma unroll
            for (int j = 0; j < 4; ++j) {
                uint4 va = *(const uint4*)(asrc + j * 8);
                *(uint4*)(At + r * 128 + (((unsigned)(h * 64 + j * 16)) ^ rsw)) = va;
                uint4 vw = *(const uint4*)(wsrc + j * 8);
                *(uint4*)(Wt + r * 128 + (((unsigned)(h * 64 + j * 16)) ^ rsw)) = vw;
            }
        }
        __syncthreads();
        #pragma unroll
        for (int sub = 0; sub < 2; ++sub) {
            bf16x8 af[4], bfr[4];
            int kbyte = sub * 64 + (lane >> 4) * 16;
            #pragma unroll
            for (int ni = 0; ni < 4; ++ni) {
                int rr = (w & 1) * 64 + ni * 16 + (lane & 15);
                af[ni] = *(const bf16x8*)(Wt + rr * 128 + ((unsigned)kbyte ^ ((unsigned)((rr & 7) << 4))));
            }
            #pragma unroll
            for (int mi = 0; mi < 4; ++mi) {
                int rr = (w >> 1) * 64 + mi * 16 + (lane & 15);
                bfr[mi] = *(const bf16x8*)(At + rr * 128 + ((unsigned)kbyte ^ ((unsigned)((rr & 7) << 4))));
            }
            #pragma unroll
            for (int mi = 0; mi < 4; ++mi)
                #pragma unroll
                for (int ni = 0; ni < 4; ++ni)
                    acc[mi][ni] = __builtin_amdgcn_mfma_f32_16x16x32_bf16(
                        af[ni], bfr[mi], acc[mi][ni], 0, 0, 0);
        }
        __syncthreads();
    }
    // epilogue: float4 (4 gates of one unit) -> Gt[slice][t][b][uloc][g]
    #pragma unroll
    for (int mi = 0; mi < 4; ++mi) {
        int mp = m0 + (w >> 1) * 64 + mi * 16 + (lane & 15);
        int t = mp >> 5, b = mp & 31;
        #pragma unroll
        for (int ni = 0; ni < 4; ++ni) {
            int npb = n0 + (w & 1) * 64 + ni * 16 + (lane >> 4) * 4;
            int unit = npb >> 2;
            float4 bv = *(const float4*)(bc + npb);
            f32x4 a = acc[mi][ni];
            float4 o = make_float4(a[0] + bv.x, a[1] + bv.y, a[2] + bv.z, a[3] + bv.w);
            *(float4*)(Gt + ((size_t)((unit >> 4) * NS + t)) * 2048 + b * 64 + (unit & 15) * 4) = o;
        }
    }
}

// ---------------------------------------------------------------------------
// MFMA persistent LSTM recurrence: R7 structure with STORE-PUBLISH barrier.
// Grid = 64 WGs: wg&1 = dir, wg>>1 = slice (16 units). Wave w owns gate-rows
// 16w..16w+15; each wave computes both batch halves from the 32KB
// XOR-swizzled bf16 LDS copy of h (proven R7 compute path, bit-identical).
// Barrier change (only): instead of 64 serialized fetch_adds on 4 lines,
// each WG STORES step+1 to its own 64B line (32 parallel stores, no RMW
// serialization); ALL waves poll the 32 lines in parallel (lane&31) with
// relaxed agent loads + __all — no tid0 bottleneck, no post-poll
// __syncthreads (LDS ordering already covered by the pre-publish sync;
// staging writes are per-thread disjoint). Monotonic step+1 values,
// zeroed per launch. Final step skips publish/poll.
// ---------------------------------------------------------------------------
__global__ __launch_bounds__(256) void k_lstm_p(const float* __restrict__ Gt,
                                                const float* __restrict__ Whh,
                                                u16* __restrict__ hxb,
                                                int* __restrict__ cblk) {
    __shared__ char hlds[NB * NHD * 2];    // 32 KB bf16, swizzled
    int wg = blockIdx.x;
    int d = wg & 1;
    int slice = wg >> 1;            // 0..31
    int n0 = slice * UPW;
    int tid = threadIdx.x;
    int lane = tid & 63;
    int w = tid >> 6;               // wave 0..3
    int* lines  = cblk + d * 512;          // 32 lines x 16 ints (64B apart)
    int* myline = lines + slice * 16;
    int pollidx = (lane & 31) * 16;        // each lane polls one line (2x cover)
    u16* hxd = hxb + (size_t)d * NS * NB * NHD;
    const float* Gd = Gt + (size_t)d * GT_DIR + (size_t)slice * NS * 2048;

    // resident A fragments (Whh fp32 -> bf16); per-wave-unique rows
    bf16x8 wfrag[16];
    {
        int rloc = lane & 15;
        int usub = rloc >> 2, g = rloc & 3;
        int kb = lane >> 4;
        const float* wrow = Whh + ((size_t)d * NG + g * NHD + n0 + 4 * w + usub) * NHD;
        #pragma unroll
        for (int kk = 0; kk < 16; ++kk) {
            const float* p = wrow + kk * 32 + kb * 8;
            float4 x = *(const float4*)p;
            float4 y = *(const float4*)(p + 4);
            bf16x8 wf;
            wf[0] = (short)f2bf(x.x); wf[1] = (short)f2bf(x.y);
            wf[2] = (short)f2bf(x.z); wf[3] = (short)f2bf(x.w);
            wf[4] = (short)f2bf(y.x); wf[5] = (short)f2bf(y.y);
            wf[6] = (short)f2bf(y.z); wf[7] = (short)f2bf(y.w);
            wfrag[kk] = wf;
        }
    }
    int uloc  = 4 * w + (lane >> 4);       // C-layout unit within slice
    int unitC = n0 + uloc;                 // global unit
    int bcol0 = lane & 15;                 // batch, tile 0
    int bcol1 = 16 + bcol0;                // batch, tile 1
    int kb    = lane >> 4;                 // B k-block
    int c8 = tid & 7, bRow = tid >> 3;     // staging role

    float c0 = 0.f, c1 = 0.f;
    // prologue: G prefetch for step 0
    int ttp = d ? (NS - 1) : 0;
    float4 Gv0 = *(const float4*)(Gd + (size_t)ttp * 2048 + bcol0 * 64 + uloc * 4);
    float4 Gv1 = *(const float4*)(Gd + (size_t)ttp * 2048 + bcol1 * 64 + uloc * 4);

    for (int step = 0; step < NS; ++step) {
        int tt = d ? (NS - 1 - step) : step;
        f32x4 acc0 = {0.f, 0.f, 0.f, 0.f};
        f32x4 acc1 = {0.f, 0.f, 0.f, 0.f};
        if (step) {
            int tprev = d ? tt + 1 : tt - 1;
            // stage hx_bf[tprev] (32KB) -> swizzled LDS: one coalesced burst
            const u16* srow = hxd + ((size_t)tprev * NB + bRow) * NHD;
            char* dstrow = hlds + bRow * 1024;
            unsigned rsw = (unsigned)((bRow & 7) << 4);
            #pragma unroll
            for (int i = 0; i < 8; ++i) {
                uint4 v = *(const uint4*)(srow + c8 * 64 + i * 8);
                *(uint4*)(dstrow + (((unsigned)(c8 * 128 + i * 16)) ^ rsw)) = v;
            }
            __syncthreads();
            const char* b0base = hlds + bcol0 * 1024;
            const char* b1base = hlds + bcol1 * 1024;
            unsigned s0 = (unsigned)((bcol0 & 7) << 4);
            unsigned s1 = (unsigned)((bcol1 & 7) << 4);
            #pragma unroll
            for (int kk = 0; kk < 16; ++kk) {
                bf16x8 b0 = *(const bf16x8*)(b0base + (((unsigned)(kk * 64 + kb * 16)) ^ s0));
                bf16x8 b1 = *(const bf16x8*)(b1base + (((unsigned)(kk * 64 + kb * 16)) ^ s1));
                acc0 = __builtin_amdgcn_mfma_f32_16x16x32_bf16(wfrag[kk], b0, acc0, 0, 0, 0);
                acc1 = __builtin_amdgcn_mfma_f32_16x16x32_bf16(wfrag[kk], b1, acc1, 0, 0, 0);
            }
        }
        // gates (reg q = gate q: i,f,g,o) for (unitC, bcol0/1)
        {
            float ig = sigm(acc0[0] + Gv0.x);
            float fg = sigm(acc0[1] + Gv0.y);
            float gg = tanhf(acc0[2] + Gv0.z);
            float og = sigm(acc0[3] + Gv0.w);
            c0 = fg * c0 + ig * gg;
            float hv = og * tanhf(c0);
            __hip_atomic_store(hxd + ((size_t)tt * NB + bcol0) * NHD + unitC, f2bf(hv),
                               __ATOMIC_RELAXED, __HIP_MEMORY_SCOPE_AGENT);
        }
        {
            float ig = sigm(acc1[0] + Gv1.x);
            float fg = sigm(acc1[1] + Gv1.y);
            float gg = tanhf(acc1[2] + Gv1.z);
            float og = sigm(acc1[3] + Gv1.w);
            c1 = fg * c1 + ig * gg;
            float hv = og * tanhf(c1);
            __hip_atomic_store(hxd + ((size_t)tt * NB + bcol1) * NHD + unitC, f2bf(hv),
                               __ATOMIC_RELAXED, __HIP_MEMORY_SCOPE_AGENT);
        }
        if (step == NS - 1) break;          // last step: no exchange needed
        // every wave: own stores complete, then WG-wide rendezvous
        asm volatile("s_waitcnt vmcnt(0)" ::: "memory");
        __syncthreads();           // all h stores done; all LDS reads done
        // publish: one relaxed store to own line (no RMW, no serialization)
        if (tid == 0)
            __hip_atomic_store(myline, step + 1, __ATOMIC_RELAXED,
                               __HIP_MEMORY_SCOPE_AGENT);
        // prefetch next step's G (hides under the poll)
        {
            int ttn = d ? tt - 1 : tt + 1;
            Gv0 = *(const float4*)(Gd + (size_t)ttn * 2048 + bcol0 * 64 + uloc * 4);
            Gv1 = *(const float4*)(Gd + (size_t)ttn * 2048 + bcol1 * 64 + uloc * 4);
        }
        asm volatile("" ::: "memory");   // pin prefetch issue before poll
        // all waves poll all 32 lines in parallel (no tid0 bottleneck,
        // no post-poll syncthreads needed: staging writes are per-thread
        // disjoint and prior LDS reads were fenced by the sync above)
        {
            int target = step + 1;
            for (;;) {
                int v = __hip_atomic_load(lines + pollidx, __ATOMIC_RELAXED,
                                          __HIP_MEMORY_SCOPE_AGENT);
                if (__all(v >= target)) break;
                __builtin_amdgcn_s_sleep(1);
            }
        }
    }
}

// ---------------------------------------------------------------------------
// MLP stage 1: mid[512][1024] = relu(hrow @ W1^T + b1), rows from hx_bf
// ---------------------------------------------------------------------------
__global__ __launch_bounds__(256) void k_mlp1(const u16* __restrict__ hxb,
                                              const int* __restrict__ pidx,
                                              const float* __restrict__ W1,
                                              const float* __restrict__ b1,
                                              float* __restrict__ mid) {
    __shared__ float As[16][65];
    __shared__ float Ws[16][65];
    int tid = threadIdx.x;
    int tx = tid & 15, ty = tid >> 4;
    int n0 = blockIdx.x * 64, m0 = blockIdx.y * 64;
    int lr = tid >> 2;
    int lk = (tid & 3) * 4;
    int m = m0 + lr;
    int bb = m >> 4;
    int s = pidx[m];
    float acc[4][4] = {};
    for (int kt = 0; kt < GK; kt += 16) {
        int k0 = kt + lk;
        int half = k0 >> 9;
        ushort4 av4 = *(const ushort4*)(hxb + (((size_t)(half * NS + s)) * NB + bb) * NHD + (k0 & 511));
        float4 wv = *(const float4*)(W1 + (size_t)(n0 + lr) * GK + k0);
        As[lk + 0][lr] = bf2f(av4.x); As[lk + 1][lr] = bf2f(av4.y);
        As[lk + 2][lr] = bf2f(av4.z); As[lk + 3][lr] = bf2f(av4.w);
        Ws[lk + 0][lr] = wv.x; Ws[lk + 1][lr] = wv.y;
        Ws[lk + 2][lr] = wv.z; Ws[lk + 3][lr] = wv.w;
        __syncthreads();
        #pragma unroll
        for (int kk = 0; kk < 16; ++kk) {
            float a[4], wv2[4];
            #pragma unroll
            for (int i = 0; i < 4; ++i) a[i] = As[kk][ty * 4 + i];
            #pragma unroll
            for (int j = 0; j < 4; ++j) wv2[j] = Ws[kk][tx * 4 + j];
            #pragma unroll
            for (int i = 0; i < 4; ++i)
                #pragma unroll
                for (int j = 0; j < 4; ++j) acc[i][j] += a[i] * wv2[j];
        }
        __syncthreads();
    }
    #pragma unroll
    for (int j = 0; j < 4; ++j) {
        int n = n0 + tx * 4 + j;
        float bias = b1[n];
        #pragma unroll
        for (int i = 0; i < 4; ++i)
            mid[(size_t)(m0 + ty * 4 + i) * 1024 + n] = fmaxf(acc[i][j] + bias, 0.f);
    }
}

// ---------------------------------------------------------------------------
// MLP stage 2: out[b, s] = mid @ W2^T + b2 + pemb[p], scattered to d_out.
// ---------------------------------------------------------------------------
__global__ __launch_bounds__(256) void k_mlp2(const float* __restrict__ mid,
                                              const int* __restrict__ pidx,
                                              const float* __restrict__ W2,
                                              const float* __restrict__ b2,
                                              const float* __restrict__ pemb,
                                              float* __restrict__ out) {
    __shared__ float As[16][65];
    __shared__ float Ws[16][65];
    int tid = threadIdx.x;
    int tx = tid & 15, ty = tid >> 4;
    int n0 = blockIdx.x * 64, m0 = blockIdx.y * 64;
    int lr = tid >> 2;
    int lk = (tid & 3) * 4;
    float acc[4][4] = {};
    for (int kt = 0; kt < GK; kt += 16) {
        float4 av = *(const float4*)(mid + (size_t)(m0 + lr) * GK + kt + lk);
        float4 wv = *(const float4*)(W2 + (size_t)(n0 + lr) * GK + kt + lk);
        As[lk + 0][lr] = av.x; As[lk + 1][lr] = av.y;
        As[lk + 2][lr] = av.z; As[lk + 3][lr] = av.w;
        Ws[lk + 0][lr] = wv.x; Ws[lk + 1][lr] = wv.y;
        Ws[lk + 2][lr] = wv.z; Ws[lk + 3][lr] = wv.w;
        __syncthreads();
        #pragma unroll
        for (int kk = 0; kk < 16; ++kk) {
            float a[4], wv2[4];
            #pragma unroll
            for (int i = 0; i < 4; ++i) a[i] = As[kk][ty * 4 + i];
            #pragma unroll
            for (int j = 0; j < 4; ++j) wv2[j] = Ws[kk][tx * 4 + j];
            #pragma unroll
            for (int i = 0; i < 4; ++i)
                #pragma unroll
                for (int j = 0; j < 4; ++j) acc[i][j] += a[i] * wv2[j];
        }
        __syncthreads();
    }
    #pragma unroll
    for (int i = 0; i < 4; ++i) {
        int m = m0 + ty * 4 + i;
        int bb = m >> 4, p = m & 15;
        int s = pidx[m];
        float* orow = out + ((size_t)(bb * NS + s)) * NE;
        const float* prow = pemb + (size_t)p * NE;
        #pragma unroll
        for (int j = 0; j < 4; ++j) {
            int n = n0 + tx * 4 + j;
            orow[n] = acc[i][j] + b2[n] + prow[n];
        }
    }
}

// ---------------------------------------------------------------------------
extern "C" void kernel_launch(void* const* d_in, const int* in_sizes, int n_in,
                              void* d_out, int out_size, void* d_ws, size_t ws_size,
                              hipStream_t stream) {
    const float* emb  = (const float*)d_in[0];
    const float* ctx  = (const float*)d_in[1];
    const float* pemb = (const float*)d_in[2];
    const float* Wih0 = (const float*)d_in[3];
    const float* Whh0 = (const float*)d_in[4];
    const float* bih0 = (const float*)d_in[5];
    const float* bhh0 = (const float*)d_in[6];
    const float* Wih1 = (const float*)d_in[7];
    const float* Whh1 = (const float*)d_in[8];
    const float* bih1 = (const float*)d_in[9];
    const float* bhh1 = (const float*)d_in[10];
    const float* W1   = (const float*)d_in[11];
    const float* b1   = (const float*)d_in[12];
    const float* W2   = (const float*)d_in[13];
    const float* b2   = (const float*)d_in[14];
    const int* ids    = (const int*)d_in[15];
    const int* pidx   = (const int*)d_in[16];
    float* out = (float*)d_out;

    // Workspace layout (bytes):
    //   Gt:    [2][32][256][2048] f32 = 134217728
    //   allb:  [256][32][1024] bf16   =  16777216
    //   hx_bf: [2][256][32][512] bf16 =  16777216
    //   Wbf:   [2][2048][1024] bf16   =   8388608
    //   biasC: [2][2048] f32          =     16384
    //   mid:   [512][1024] f32        =   2097152
    //   ctr:   2048 ints (2 layers x 2 dirs x 32 lines x 16 ints)
    char* ws = (char*)d_ws;
    float* Gt    = (float*)ws;
    u16*   allb  = (u16*)(ws + 134217728u);
    u16*   hx    = (u16*)(ws + 150994944u);
    u16*   Wbf   = (u16*)(ws + 167772160u);
    float* biasC = (float*)(ws + 176160768u);
    float* mid   = (float*)(ws + 176177152u);
    int*   ctr   = (int*)(ws + 178274304u);

    k_zero<<<dim3(8), dim3(256), 0, stream>>>(ctr);
    k_allb<<<dim3(NBS), dim3(256), 0, stream>>>(emb, ctx, pemb, ids, pidx, allb);

    // Layer 0
    k_wcvt<<<dim3(2 * NG), dim3(256), 0, stream>>>(Wih0, bih0, bhh0, Wbf, biasC);
    for (int d = 0; d < 2; ++d)
        k_gemm_m<<<dim3(NG / 128, NBS / 128), dim3(256), 0, stream>>>(
            allb, allb + 512, 1024, Wbf + (size_t)d * NG * GK, biasC + d * NG,
            Gt + (size_t)d * GT_DIR);
    k_lstm_p<<<dim3(2 * NWGD), dim3(256), 0, stream>>>(Gt, Whh0, hx, ctr);

    k_raw<<<dim3(NBS), dim3(256), 0, stream>>>(emb, ids, out);

    // Layer 1 (A = hx_bf, dir halves)
    k_wcvt<<<dim3(2 * NG), dim3(256), 0, stream>>>(Wih1, bih1, bhh1, Wbf, biasC);
    for (int d = 0; d < 2; ++d)
        k_gemm_m<<<dim3(NG / 128, NBS / 128), dim3(256), 0, stream>>>(
            hx, hx + (size_t)NS * NB * NHD, 512, Wbf + (size_t)d * NG * GK,
            biasC + d * NG, Gt + (size_t)d * GT_DIR);
    k_lstm_p<<<dim3(2 * NWGD), dim3(256), 0, stream>>>(Gt, Whh1, hx, ctr + 1024);

    // MLP head at prompt rows
    k_mlp1<<<dim3(16, 8), dim3(256), 0, stream>>>(hx, pidx, W1, b1, mid);
    k_mlp2<<<dim3(16, 8), dim3(256), 0, stream>>>(mid, pidx, W2, b2, pemb, out);
}